// Round 8
// baseline (493.213 us; speedup 1.0000x reference)
//
#include <hip/hip_runtime.h>
#include <stdint.h>

typedef unsigned short u16;
typedef __attribute__((ext_vector_type(8))) short short8;
typedef __attribute__((ext_vector_type(4))) float floatx4;

#define MFMA_BF16 __builtin_amdgcn_mfma_f32_16x16x32_bf16

// dims
#define BB 4
#define TT 2048
#define CC 1024
#define HH 16
#define DH 64
#define MM (BB * TT)      // 8192
#define NQKV (3 * CC)     // 3072

__device__ __forceinline__ u16 f2bf(float f) {
  union { float f; uint32_t u; } un;
  un.f = f;
  uint32_t u = un.u;
  u += 0x7fffu + ((u >> 16) & 1u);   // round-to-nearest-even
  return (u16)(u >> 16);
}

__device__ __forceinline__ uint32_t pk2(float a, float b) {
  return (uint32_t)f2bf(a) | ((uint32_t)f2bf(b) << 16);
}

// pack hi16(a) | hi16(b)<<16 in ONE v_perm_b32 (truncating bf16 round)
__device__ __forceinline__ uint32_t pktrunc(float a, float b) {
  union { float f; uint32_t u; } ua, ub;
  ua.f = a; ub.f = b;
  return __builtin_amdgcn_perm(ub.u, ua.u, 0x07060302u);
}

// async global->LDS, 16B per lane. lds dst = wave-uniform base + lane*16.
__device__ __forceinline__ void gload_lds16(const u16* g, u16* l) {
  __builtin_amdgcn_global_load_lds(
      (const __attribute__((address_space(1))) unsigned int*)g,
      (__attribute__((address_space(3))) unsigned int*)l, 16, 0, 0);
}

// raw barrier with compiler-level memory fence (no vmcnt/lgkm drain)
__device__ __forceinline__ void BAR() {
  asm volatile("" ::: "memory");
  __builtin_amdgcn_s_barrier();
  asm volatile("" ::: "memory");
}

// ---------------------------------------------------------------------------
// Kernel 0: fp32 -> bf16 conversions + coalesced weight transpose.
// ---------------------------------------------------------------------------
__global__ __launch_bounds__(256) void convert_kernel(
    const float* __restrict__ x, const float* __restrict__ Wq,
    const float* __restrict__ Wk, const float* __restrict__ Wv,
    const float* __restrict__ Wo, u16* __restrict__ xb,
    u16* __restrict__ Wt, u16* __restrict__ Wob) {
  __shared__ float T[32][33];
  int bid = blockIdx.x, tid = threadIdx.x;
  if (bid < 8192) {
    int i = (bid * 256 + tid) * 4;
    float4 f = *(const float4*)(x + i);
    uint2 o = {pk2(f.x, f.y), pk2(f.z, f.w)};
    *(uint2*)(xb + i) = o;
  } else if (bid < 8192 + 3072) {
    int tb = bid - 8192;
    int sec = tb >> 10, rem = tb & 1023;
    int h = rem >> 6, sub = rem & 63, ct = sub >> 1, dt = sub & 1;
    const float* W = (sec == 0) ? Wq : (sec == 1) ? Wk : Wv;
    int tx = tid & 31, ty = tid >> 5;
#pragma unroll
    for (int p = 0; p < 4; ++p)
      T[ty + 8 * p][tx] =
          W[((size_t)h * CC + ct * 32 + ty + 8 * p) * DH + dt * 32 + tx];
    __syncthreads();
#pragma unroll
    for (int p = 0; p < 4; ++p) {
      int n = sec * 1024 + h * 64 + dt * 32 + ty + 8 * p;
      Wt[(size_t)n * CC + ct * 32 + tx] = f2bf(T[tx][ty + 8 * p]);
    }
  } else {
    int i = ((bid - 11264) * 256 + tid) * 4;
    float4 f = *(const float4*)(Wo + i);
    uint2 o = {pk2(f.x, f.y), pk2(f.z, f.w)};
    *(uint2*)(Wob + i) = o;
  }
}

// ---------------------------------------------------------------------------
// QKV GEMM, phase-locked pipeline (measured equal to coarse variant).
// ---------------------------------------------------------------------------
__global__ __launch_bounds__(512, 2) void gemm_qkv(
    const u16* __restrict__ A, const u16* __restrict__ Bt,
    u16* __restrict__ qout, u16* __restrict__ kout, u16* __restrict__ vout) {
  __shared__ u16 As[3 * 128 * 32];  // 24 KB, slot stride 4096 elems
  __shared__ u16 Bs[3 * 384 * 32];  // 72 KB, slot stride 12288 elems

  int tid = threadIdx.x;
  int lane = tid & 63, w = tid >> 6;
  int wr = w >> 2, wc = w & 3;
  int g = lane >> 4, c = lane & 15;
  int m0 = blockIdx.y * 128, n0 = blockIdx.x * 384;

  floatx4 acc[4][6];
#pragma unroll
  for (int i = 0; i < 4; ++i)
#pragma unroll
    for (int j = 0; j < 6; ++j) acc[i][j] = (floatx4){0.f, 0.f, 0.f, 0.f};

  int arow = tid >> 2, acol = (tid & 3) * 8;
  const u16* Ag = A + (size_t)(m0 + arow) * CC + acol;
  const u16* Bg = Bt + (size_t)(n0 + arow) * CC + acol;
  u16* asd = As + tid * 8;
  u16* bsd = Bs + tid * 8;

  int aro = (wr * 64 + c) * 32 + g * 8;   // + mt*512
  int bro = (wc * 96 + c) * 32 + g * 8;   // + nt*512

  // prologue: stage tile 0 -> slot 0, tile 1 -> slot 1
  gload_lds16(Ag, asd);
  gload_lds16(Bg, bsd);
  gload_lds16(Bg + (size_t)128 * CC, bsd + 4096);
  gload_lds16(Bg + (size_t)256 * CC, bsd + 8192);
  gload_lds16(Ag + 32, asd + 4096);
  gload_lds16(Bg + 32, bsd + 12288);
  gload_lds16(Bg + 32 + (size_t)128 * CC, bsd + 12288 + 4096);
  gload_lds16(Bg + 32 + (size_t)256 * CC, bsd + 12288 + 8192);
  asm volatile("s_waitcnt vmcnt(4)" ::: "memory");  // tile 0 resident
  BAR();

#define QTILE(SCA, SCB, SPA, SPB, T2, STG, VMW)                               \
  {                                                                           \
    short8 af0 = *(const short8*)(As + (SCA) + aro);                          \
    short8 af1 = *(const short8*)(As + (SCA) + aro + 512);                    \
    short8 af2 = *(const short8*)(As + (SCA) + aro + 1024);                   \
    short8 af3 = *(const short8*)(As + (SCA) + aro + 1536);                   \
    short8 bv0 = *(const short8*)(Bs + (SCB) + bro);                          \
    short8 bv1 = *(const short8*)(Bs + (SCB) + bro + 512);                    \
    short8 bv2 = *(const short8*)(Bs + (SCB) + bro + 1024);                   \
    if (STG) {                                                                \
      gload_lds16(Ag + (size_t)(T2) * 32, asd + (SPA));                       \
      gload_lds16(Bg + (size_t)(T2) * 32, bsd + (SPB));                       \
    }                                                                         \
    BAR();                                                                    \
    __builtin_amdgcn_s_setprio(1);                                            \
    acc[0][0] = MFMA_BF16(af0, bv0, acc[0][0], 0, 0, 0);                      \
    acc[0][1] = MFMA_BF16(af0, bv1, acc[0][1], 0, 0, 0);                      \
    acc[0][2] = MFMA_BF16(af0, bv2, acc[0][2], 0, 0, 0);                      \
    acc[1][0] = MFMA_BF16(af1, bv0, acc[1][0], 0, 0, 0);                      \
    acc[1][1] = MFMA_BF16(af1, bv1, acc[1][1], 0, 0, 0);                      \
    acc[1][2] = MFMA_BF16(af1, bv2, acc[1][2], 0, 0, 0);                      \
    acc[2][0] = MFMA_BF16(af2, bv0, acc[2][0], 0, 0, 0);                      \
    acc[2][1] = MFMA_BF16(af2, bv1, acc[2][1], 0, 0, 0);                      \
    acc[2][2] = MFMA_BF16(af2, bv2, acc[2][2], 0, 0, 0);                      \
    acc[3][0] = MFMA_BF16(af3, bv0, acc[3][0], 0, 0, 0);                      \
    acc[3][1] = MFMA_BF16(af3, bv1, acc[3][1], 0, 0, 0);                      \
    acc[3][2] = MFMA_BF16(af3, bv2, acc[3][2], 0, 0, 0);                      \
    __builtin_amdgcn_s_setprio(0);                                            \
    BAR();                                                                    \
    short8 bv3 = *(const short8*)(Bs + (SCB) + bro + 1536);                   \
    short8 bv4 = *(const short8*)(Bs + (SCB) + bro + 2048);                   \
    short8 bv5 = *(const short8*)(Bs + (SCB) + bro + 2560);                   \
    if (STG) {                                                                \
      gload_lds16(Bg + (size_t)(T2) * 32 + (size_t)128 * CC,                  \
                  bsd + (SPB) + 4096);                                        \
      gload_lds16(Bg + (size_t)(T2) * 32 + (size_t)256 * CC,                  \
                  bsd + (SPB) + 8192);                                        \
    }                                                                         \
    BAR();                                                                    \
    __builtin_amdgcn_s_setprio(1);                                            \
    acc[0][3] = MFMA_BF16(af0, bv3, acc[0][3], 0, 0, 0);                      \
    acc[0][4] = MFMA_BF16(af0, bv4, acc[0][4], 0, 0, 0);                      \
    acc[0][5] = MFMA_BF16(af0, bv5, acc[0][5], 0, 0, 0);                      \
    acc[1][3] = MFMA_BF16(af1, bv3, acc[1][3], 0, 0, 0);                      \
    acc[1][4] = MFMA_BF16(af1, bv4, acc[1][4], 0, 0, 0);                      \
    acc[1][5] = MFMA_BF16(af1, bv5, acc[1][5], 0, 0, 0);                      \
    acc[2][3] = MFMA_BF16(af2, bv3, acc[2][3], 0, 0, 0);                      \
    acc[2][4] = MFMA_BF16(af2, bv4, acc[2][4], 0, 0, 0);                      \
    acc[2][5] = MFMA_BF16(af2, bv5, acc[2][5], 0, 0, 0);                      \
    acc[3][3] = MFMA_BF16(af3, bv3, acc[3][3], 0, 0, 0);                      \
    acc[3][4] = MFMA_BF16(af3, bv4, acc[3][4], 0, 0, 0);                      \
    acc[3][5] = MFMA_BF16(af3, bv5, acc[3][5], 0, 0, 0);                      \
    __builtin_amdgcn_s_setprio(0);                                            \
    VMW;                                                                      \
    BAR();                                                                    \
  }

  int scA = 0, snA = 4096, spA = 8192;
  int scB = 0, snB = 12288, spB = 24576;
#pragma unroll 1
  for (int t = 0; t < 30; ++t) {
    QTILE(scA, scB, spA, spB, t + 2, 1,
          asm volatile("s_waitcnt vmcnt(4)" ::: "memory"));
    int ta = scA; scA = snA; snA = spA; spA = ta;
    int tb = scB; scB = snB; snB = spB; spB = tb;
  }
  QTILE(scA, scB, spA, spB, 0, 0,
        asm volatile("s_waitcnt vmcnt(0)" ::: "memory"));
  {
    int ta = scA; scA = snA; snA = spA; spA = ta;
    int tb = scB; scB = snB; snB = spB; spB = tb;
  }
  QTILE(scA, scB, spA, spB, 0, 0, (void)0);
#undef QTILE

  // epilogue: scatter to q/k/v in [bh][t][d] layout (16-lane d-contiguous)
  int mrow = m0 + wr * 64 + g * 4;
  int ncol = n0 + wc * 96 + c;
#pragma unroll
  for (int nt = 0; nt < 6; ++nt) {
    int n = ncol + nt * 16;
    int sec = n >> 10, h = (n >> 6) & 15, d = n & 63;
    u16* dst = (sec == 0) ? qout : (sec == 1) ? kout : vout;
    float sc = (sec == 0) ? 0.18033688011112042f : 1.f;
    // ^ DH^-0.5 * log2(e): softmax runs in exp2 domain
#pragma unroll
    for (int mt = 0; mt < 4; ++mt) {
#pragma unroll
      for (int r = 0; r < 4; ++r) {
        int m = mrow + mt * 16 + r;
        int b = m >> 11, t = m & 2047;
        dst[(((size_t)(b * HH + h)) * TT + t) * DH + d] =
            f2bf(acc[mt][nt][r] * sc);
      }
    }
  }
}

// ---------------------------------------------------------------------------
// GEMM: C[M,N] = A[M,K] @ Bt[N,K]^T, bf16 in, fp32 accum. m97 pattern.
// (now used only as MODE 1: output projection +bias fp32)
// ---------------------------------------------------------------------------
template <int MODE>
__global__ __launch_bounds__(256) void gemm_bt(
    const u16* __restrict__ A, const u16* __restrict__ Bt, int M, int N, int K,
    u16* __restrict__ qout, u16* __restrict__ kout, u16* __restrict__ vout,
    float* __restrict__ out, const float* __restrict__ bias) {
  __shared__ u16 As[128][64];  // unpadded: required by global_load_lds
  __shared__ u16 Bs[128][64];
  int tid = threadIdx.x;
  int lane = tid & 63, w = tid >> 6;
  int wm = w >> 1, wn = w & 1;
  int g = lane >> 4, c = lane & 15;
  int m0 = blockIdx.y * 128, n0 = blockIdx.x * 128;

  floatx4 acc[4][4];
#pragma unroll
  for (int i = 0; i < 4; ++i)
#pragma unroll
    for (int j = 0; j < 4; ++j) acc[i][j] = (floatx4){0.f, 0.f, 0.f, 0.f};

  int srow = 32 * w + (lane >> 3);
  int scol = (lane & 7) * 8;
  const u16* Ag = A + (size_t)(m0 + srow) * K + scol;
  const u16* Bg = Bt + (size_t)(n0 + srow) * K + scol;
  u16* AsB = &As[32 * w][0];
  u16* BsB = &Bs[32 * w][0];

  for (int k0 = 0; k0 < K; k0 += 64) {
    __syncthreads();
#pragma unroll
    for (int j = 0; j < 4; ++j)
      gload_lds16(Ag + k0 + (size_t)j * 8 * K, AsB + j * 512);
#pragma unroll
    for (int j = 0; j < 4; ++j)
      gload_lds16(Bg + k0 + (size_t)j * 8 * K, BsB + j * 512);
    __syncthreads();
#pragma unroll
    for (int kc = 0; kc < 2; ++kc) {
      short8 af[4], bfv[4];
#pragma unroll
      for (int mt = 0; mt < 4; ++mt)
        af[mt] = *(const short8*)(&As[wm * 64 + mt * 16 + c][kc * 32 + g * 8]);
#pragma unroll
      for (int nt = 0; nt < 4; ++nt)
        bfv[nt] = *(const short8*)(&Bs[wn * 64 + nt * 16 + c][kc * 32 + g * 8]);
#pragma unroll
      for (int mt = 0; mt < 4; ++mt)
#pragma unroll
        for (int nt = 0; nt < 4; ++nt)
          acc[mt][nt] = MFMA_BF16(af[mt], bfv[nt], acc[mt][nt], 0, 0, 0);
    }
  }

#pragma unroll
  for (int mt = 0; mt < 4; ++mt) {
#pragma unroll
    for (int nt = 0; nt < 4; ++nt) {
#pragma unroll
      for (int r = 0; r < 4; ++r) {
        int m = m0 + wm * 64 + mt * 16 + g * 4 + r;  // C-layout: row=(lane>>4)*4+reg
        int n = n0 + wn * 64 + nt * 16 + c;          //           col=lane&15
        float v = acc[mt][nt][r];
        if (MODE == 0) {
          int b = m >> 11, t = m & 2047;
          int sec = n >> 10, h = (n >> 6) & 15, d = n & 63;
          size_t idx = (((size_t)(b * HH + h)) * TT + t) * DH + d;
          if (sec == 0)
            qout[idx] = f2bf(v * 0.18033688011112042f);
          else if (sec == 1)
            kout[idx] = f2bf(v);
          else
            vout[idx] = f2bf(v);
        } else {
          out[(size_t)m * N + n] = v + bias[n];
        }
      }
    }
  }
}

// ---------------------------------------------------------------------------
// V permute-transpose: v[bh][s][d] -> vP[bh][d][tile][u] where
// s = tile*64 + (u&3)*16 + (u>>2)  (i.e. u = 4*(s&15) + ((s>>4)&3)).
// ---------------------------------------------------------------------------
__global__ __launch_bounds__(256) void vtrans(const u16* __restrict__ v,
                                              u16* __restrict__ vP) {
  __shared__ u16 Ld[64][72];
  int tile = blockIdx.x, bh = blockIdx.y, tid = threadIdx.x;
  int row = tid >> 2, col = (tid & 3) * 16;
  const u16* src = v + ((size_t)bh * TT + tile * 64 + row) * DH + col;
  *(uint4*)(&Ld[row][col]) = *(const uint4*)(src);
  *(uint4*)(&Ld[row][col + 8]) = *(const uint4*)(src + 8);
  __syncthreads();
  int d = tid >> 2, u0 = (tid & 3) * 16;
  union { u16 h[16]; uint4 q[2]; } o;
#pragma unroll
  for (int k = 0; k < 16; ++k) {
    int u = u0 + k;
    int s = ((u & 3) << 4) | (u >> 2);
    o.h[k] = Ld[s][d];
  }
  u16* dst = vP + ((size_t)(bh * DH + d)) * TT + tile * 64 + u0;
  *(uint4*)(dst) = o.q[0];
  *(uint4*)(dst + 8) = o.q[1];
}

// ---------------------------------------------------------------------------
// Causal flash, round-7 proven structure (padded-72 LDS, setprio clusters,
// pre-barrier prefetch) + TICKET-MERGE epilogue replacing the merge_heavy
// kernel: the two heavy key-halves of each (bh, q-tile) pair rendezvous via
// a device-scope atomic ticket; the SECOND finisher reads the other half's
// fp32 partials (its own are still in registers) and writes the final bf16
// rows.  fp32 own+other is commutative -> bitwise-deterministic regardless
// of which half wins.  Release/acquire via __threadfence around the atomic.
// LPT chunking: heavy q-tiles split into two key-halves; scale-free softmax
// partials merge by plain addition.
// ---------------------------------------------------------------------------
__constant__ unsigned char CHUNK_X[24] = {15, 15, 7, 14, 14, 13, 13, 6,
                                          12, 12, 11, 11, 5, 10, 10, 9,
                                          9,  4,  8,  8,  3, 2,  1,  0};
__constant__ unsigned char CHUNK_H[24] = {0, 1, 2, 0, 1, 0, 1, 2, 0, 1, 0, 1,
                                          2, 0, 1, 0, 1, 2, 0, 1, 2, 2, 2, 2};

__global__ __launch_bounds__(256, 4) void flash_attn(
    const u16* __restrict__ q, const u16* __restrict__ k,
    const u16* __restrict__ vP, u16* __restrict__ O,
    float* __restrict__ opart, float* __restrict__ lpart,
    unsigned int* __restrict__ ticket) {
  __shared__ u16 Ks[64][72];     // [s][d]
  __shared__ u16 Vs[64][72];     // [d][u]  (u = permuted s)
  __shared__ u16 Ps[4][32][72];  // per-wave P tile [m][u]
  __shared__ int role;

  int tid = threadIdx.x;
  int lane = tid & 63, w = tid >> 6;
  int g = lane >> 4, c = lane & 15;

  int id = blockIdx.x;
  int e = id >> 6, bh = id & 63;
  int x = CHUNK_X[e], hf = CHUNK_H[e];  // hf: 0/1 = key-half, 2 = whole tile
  int sb, se;
  if (hf == 2) {
    sb = 0; se = 2 * x + 2;
  } else {
    int n = x + 1; sb = hf * n; se = sb + n;
  }
  int t0 = x << 7;

  const u16* qb = q + (size_t)bh * TT * DH;
  const u16* kb = k + (size_t)bh * TT * DH;
  const u16* vb = vP + (size_t)bh * DH * TT;

  // Q fragments persistent in registers (A-layout: m=lane&15, k=(lane>>4)*8+j)
  short8 qf[2][2];
#pragma unroll
  for (int mt = 0; mt < 2; ++mt) {
    int qrow = t0 + w * 32 + mt * 16 + c;
#pragma unroll
    for (int kc = 0; kc < 2; ++kc)
      qf[mt][kc] = *(const short8*)(qb + (size_t)qrow * DH + kc * 32 + g * 8);
  }

  const floatx4 zf = {0.f, 0.f, 0.f, 0.f};
  const short8 onesf = {(short)0x3F80, (short)0x3F80, (short)0x3F80,
                        (short)0x3F80, (short)0x3F80, (short)0x3F80,
                        (short)0x3F80, (short)0x3F80};  // bf16 1.0 x8

  floatx4 oacc[2][4];
#pragma unroll
  for (int mt = 0; mt < 2; ++mt)
#pragma unroll
    for (int nt = 0; nt < 4; ++nt) oacc[mt][nt] = zf;
  floatx4 lacc[2];
  lacc[0] = zf;
  lacc[1] = zf;

  // staging: row = tid>>2 (0..63), col base = (tid&3)*16, 2x16B per tensor
  int srow = tid >> 2, scol = (tid & 3) * 16;
  const u16* kbase = kb + (size_t)srow * DH + scol;
  const u16* vbase = vb + (size_t)srow * TT + scol;  // vP rows: [d][t-contig]

  // preload iter sb
  uint4 kr0 = *(const uint4*)(kbase + (size_t)(sb << 6) * DH);
  uint4 kr1 = *(const uint4*)(kbase + (size_t)(sb << 6) * DH + 8);
  uint4 vr0 = *(const uint4*)(vbase + (sb << 6));
  uint4 vr1 = *(const uint4*)(vbase + (sb << 6) + 8);

  int nfull = 2 * x;  // iters >= nfull need the causal mask
  int wmax = t0 + w * 32 + 31;
  for (int it = sb; it < se; ++it) {
    int s0 = it << 6;
    __syncthreads();  // all waves done reading prev tiles
    *(uint4*)(&Ks[srow][scol]) = kr0;
    *(uint4*)(&Ks[srow][scol + 8]) = kr1;
    *(uint4*)(&Vs[srow][scol]) = vr0;
    *(uint4*)(&Vs[srow][scol + 8]) = vr1;
    if (it + 1 < se) {  // prefetch issued BEFORE barrier: regs already
      size_t koff = (size_t)((it + 1) << 6) * DH;  // consumed by ds_writes
      int voff = (it + 1) << 6;
      kr0 = *(const uint4*)(kbase + koff);
      kr1 = *(const uint4*)(kbase + koff + 8);
      vr0 = *(const uint4*)(vbase + voff);
      vr1 = *(const uint4*)(vbase + voff + 8);
    }
    __syncthreads();
    if (s0 > wmax) continue;  // wave-uniform: tile fully masked (last iter)
    bool masked = (it >= nfull);

    // S = Q K^T ; kf shared across both m-tiles; kc=0 uses zero C-operand
    floatx4 z[2][4];
    __builtin_amdgcn_s_setprio(1);
#pragma unroll
    for (int n = 0; n < 4; ++n) {
      short8 kf = *(const short8*)(&Ks[n * 16 + c][g * 8]);
      z[0][n] = MFMA_BF16(qf[0][0], kf, zf, 0, 0, 0);
      z[1][n] = MFMA_BF16(qf[1][0], kf, zf, 0, 0, 0);
    }
#pragma unroll
    for (int n = 0; n < 4; ++n) {
      short8 kf = *(const short8*)(&Ks[n * 16 + c][32 + g * 8]);
      z[0][n] = MFMA_BF16(qf[0][1], kf, z[0][n], 0, 0, 0);
      z[1][n] = MFMA_BF16(qf[1][1], kf, z[1][n], 0, 0, 0);
    }
    __builtin_amdgcn_s_setprio(0);

    // softmax (no offset: uniform scale cancels in the final division);
    // P packed to bf16 by v_perm truncation, b64 stores
#pragma unroll
    for (int mt = 0; mt < 2; ++mt) {
      int qr = t0 + w * 32 + mt * 16 + g * 4;
#pragma unroll
      for (int r = 0; r < 4; ++r) {
        float p0 = exp2f(z[mt][0][r]);
        float p1 = exp2f(z[mt][1][r]);
        float p2 = exp2f(z[mt][2][r]);
        float p3 = exp2f(z[mt][3][r]);
        if (masked) {
          if (s0 + c > qr + r) p0 = 0.f;
          if (s0 + 16 + c > qr + r) p1 = 0.f;
          if (s0 + 32 + c > qr + r) p2 = 0.f;
          if (s0 + 48 + c > qr + r) p3 = 0.f;
        }
        // u-layout: s = n*16+c -> u = 4c+n; 4 values contiguous at u0=4c
        uint2 pk = {pktrunc(p0, p1), pktrunc(p2, p3)};
        *(uint2*)(&Ps[w][mt * 16 + g * 4 + r][4 * c]) = pk;
      }
    }

    // PV + lsum-by-MFMA: vf shared across both m-tiles (intra-wave LDS)
    __builtin_amdgcn_s_setprio(1);
#pragma unroll
    for (int kc = 0; kc < 2; ++kc) {
      short8 pf0 = *(const short8*)(&Ps[w][c][kc * 32 + g * 8]);
      short8 pf1 = *(const short8*)(&Ps[w][16 + c][kc * 32 + g * 8]);
      lacc[0] = MFMA_BF16(pf0, onesf, lacc[0], 0, 0, 0);
      lacc[1] = MFMA_BF16(pf1, onesf, lacc[1], 0, 0, 0);
#pragma unroll
      for (int nt = 0; nt < 4; ++nt) {
        short8 vf = *(const short8*)(&Vs[nt * 16 + c][kc * 32 + g * 8]);
        oacc[0][nt] = MFMA_BF16(pf0, vf, oacc[0][nt], 0, 0, 0);
        oacc[1][nt] = MFMA_BF16(pf1, vf, oacc[1][nt], 0, 0, 0);
      }
    }
    __builtin_amdgcn_s_setprio(0);
  }

  // epilogue: lacc[mt][r] already holds the full row-sum (replicated over c)
  int b = bh >> 4, h = bh & 15;
  if (hf == 2) {
    // light chunk: normalize and write bf16 directly
#pragma unroll
    for (int mt = 0; mt < 2; ++mt) {
      float inv[4];
#pragma unroll
      for (int r = 0; r < 4; ++r) inv[r] = 1.f / lacc[mt][r];
#pragma unroll
      for (int nt = 0; nt < 4; ++nt)
#pragma unroll
        for (int r = 0; r < 4; ++r) {
          int trow = t0 + w * 32 + mt * 16 + g * 4 + r;
          O[((size_t)b * TT + trow) * CC + h * DH + nt * 16 + c] =
              f2bf(oacc[mt][nt][r] * inv[r]);
        }
    }
  } else {
    // heavy half: write fp32 partials, then rendezvous.  Second finisher
    // merges (own regs + other half's partials) and writes final bf16.
    float* os = opart + ((size_t)hf * 65536 + (size_t)bh * 1024) * 64;
    float* ls = lpart + (size_t)hf * 65536 + (size_t)bh * 1024;
    int r0b = t0 - 1024 + w * 32;  // wave's local heavy-row base
#pragma unroll
    for (int mt = 0; mt < 2; ++mt) {
      int r0 = r0b + mt * 16 + g * 4;
#pragma unroll
      for (int nt = 0; nt < 4; ++nt)
#pragma unroll
        for (int r = 0; r < 4; ++r)
          os[(size_t)(r0 + r) * 64 + nt * 16 + c] = oacc[mt][nt][r];
      if (c == 0)
#pragma unroll
        for (int r = 0; r < 4; ++r) ls[r0 + r] = lacc[mt][r];
    }
    __threadfence();  // release: partials visible device-wide before ticket
    __syncthreads();  // all threads' stores fenced before the atomic
    if (tid == 0) role = atomicAdd(&ticket[bh * 8 + (x - 8)], 1u);
    __syncthreads();
    if (role == 0) return;  // first finisher: partner will merge
    __threadfence();        // acquire: partner's partials visible
    const float* oo =
        opart + ((size_t)(hf ^ 1) * 65536 + (size_t)bh * 1024) * 64;
    const float* lo = lpart + (size_t)(hf ^ 1) * 65536 + (size_t)bh * 1024;
#pragma unroll
    for (int mt = 0; mt < 2; ++mt) {
      int r0 = r0b + mt * 16 + g * 4;
      float inv[4];
#pragma unroll
      for (int r = 0; r < 4; ++r) inv[r] = 1.f / (lacc[mt][r] + lo[r0 + r]);
#pragma unroll
      for (int nt = 0; nt < 4; ++nt)
#pragma unroll
        for (int r = 0; r < 4; ++r) {
          float ov = (oacc[mt][nt][r] +
                      oo[(size_t)(r0 + r) * 64 + nt * 16 + c]) *
                     inv[r];
          int trow = t0 + w * 32 + mt * 16 + g * 4 + r;
          O[((size_t)b * TT + trow) * CC + h * DH + nt * 16 + c] = f2bf(ov);
        }
    }
  }
}

// ---------------------------------------------------------------------------
extern "C" void kernel_launch(void* const* d_in, const int* in_sizes, int n_in,
                              void* d_out, int out_size, void* d_ws,
                              size_t ws_size, hipStream_t stream) {
  const float* x = (const float*)d_in[0];
  const float* Wq = (const float*)d_in[1];
  const float* Wk = (const float*)d_in[2];
  const float* Wv = (const float*)d_in[3];
  const float* Wo = (const float*)d_in[4];
  const float* bo = (const float*)d_in[5];
  float* out = (float*)d_out;

  u16* ws = (u16*)d_ws;
  u16* xb = ws;                        // 8388608  (reused as Ow after QKV GEMM)
  u16* Wt = xb + 8388608;              // 3145728  (dead after gemm_qkv: lpart+ticket)
  u16* Wob = Wt + 3145728;             // 1048576
  u16* qw = Wob + 1048576;             // 8388608
  u16* kw = qw + 8388608;              // 8388608
  u16* vw = kw + 8388608;              // 8388608 ([bh][t][d], coalesced)
  u16* vP = vw + 8388608;              // 8388608 (permuted [bh][d][tile][u])
  u16* Ow = xb;                        // alias: xb dead after gemm_qkv
  float* opart = (float*)d_out;        // dead until gemm<1>
  float* lpart = (float*)Wt;           // Wt dead after gemm_qkv (524288 B)
  unsigned int* ticket =
      (unsigned int*)((char*)Wt + 524288);  // 512 slots, 2 KB

  convert_kernel<<<12288, 256, 0, stream>>>(x, Wq, Wk, Wv, Wo, xb, Wt, Wob);

  gemm_qkv<<<dim3(NQKV / 384, MM / 128), 512, 0, stream>>>(
      xb, Wt, qw, kw, vw);

  vtrans<<<dim3(TT / 64, BB * HH), 256, 0, stream>>>(vw, vP);

  // zero the rendezvous tickets (stream-ordered: after gemm_qkv freed Wt)
  hipMemsetAsync(ticket, 0, 512 * sizeof(unsigned int), stream);

  flash_attn<<<dim3(1536), 256, 0, stream>>>(qw, kw, vP, Ow, opart, lpart,
                                             ticket);

  gemm_bt<1><<<dim3(CC / 128, MM / 128), 256, 0, stream>>>(
      Ow, Wob, MM, CC, CC, nullptr, nullptr, nullptr, out, bo);
}

// Round 9
// 282.643 us; speedup vs baseline: 1.7450x; 1.7450x over previous
//
#include <hip/hip_runtime.h>
#include <stdint.h>

typedef unsigned short u16;
typedef __attribute__((ext_vector_type(8))) short short8;
typedef __attribute__((ext_vector_type(4))) float floatx4;

#define MFMA_BF16 __builtin_amdgcn_mfma_f32_16x16x32_bf16

// dims
#define BB 4
#define TT 2048
#define CC 1024
#define HH 16
#define DH 64
#define MM (BB * TT)      // 8192
#define NQKV (3 * CC)     // 3072

__device__ __forceinline__ u16 f2bf(float f) {
  union { float f; uint32_t u; } un;
  un.f = f;
  uint32_t u = un.u;
  u += 0x7fffu + ((u >> 16) & 1u);   // round-to-nearest-even
  return (u16)(u >> 16);
}

__device__ __forceinline__ uint32_t pk2(float a, float b) {
  return (uint32_t)f2bf(a) | ((uint32_t)f2bf(b) << 16);
}

// pack hi16(a) | hi16(b)<<16 in ONE v_perm_b32 (truncating bf16 round)
__device__ __forceinline__ uint32_t pktrunc(float a, float b) {
  union { float f; uint32_t u; } ua, ub;
  ua.f = a; ub.f = b;
  return __builtin_amdgcn_perm(ub.u, ua.u, 0x07060302u);
}

// async global->LDS, 16B per lane. lds dst = wave-uniform base + lane*16.
__device__ __forceinline__ void gload_lds16(const u16* g, u16* l) {
  __builtin_amdgcn_global_load_lds(
      (const __attribute__((address_space(1))) unsigned int*)g,
      (__attribute__((address_space(3))) unsigned int*)l, 16, 0, 0);
}

// raw barrier with compiler-level memory fence (no vmcnt/lgkm drain)
__device__ __forceinline__ void BAR() {
  asm volatile("" ::: "memory");
  __builtin_amdgcn_s_barrier();
  asm volatile("" ::: "memory");
}

// ---------------------------------------------------------------------------
// Kernel 0: fp32 -> bf16 conversions + coalesced weight transpose.
// ---------------------------------------------------------------------------
__global__ __launch_bounds__(256) void convert_kernel(
    const float* __restrict__ x, const float* __restrict__ Wq,
    const float* __restrict__ Wk, const float* __restrict__ Wv,
    const float* __restrict__ Wo, u16* __restrict__ xb,
    u16* __restrict__ Wt, u16* __restrict__ Wob) {
  __shared__ float T[32][33];
  int bid = blockIdx.x, tid = threadIdx.x;
  if (bid < 8192) {
    int i = (bid * 256 + tid) * 4;
    float4 f = *(const float4*)(x + i);
    uint2 o = {pk2(f.x, f.y), pk2(f.z, f.w)};
    *(uint2*)(xb + i) = o;
  } else if (bid < 8192 + 3072) {
    int tb = bid - 8192;
    int sec = tb >> 10, rem = tb & 1023;
    int h = rem >> 6, sub = rem & 63, ct = sub >> 1, dt = sub & 1;
    const float* W = (sec == 0) ? Wq : (sec == 1) ? Wk : Wv;
    int tx = tid & 31, ty = tid >> 5;
#pragma unroll
    for (int p = 0; p < 4; ++p)
      T[ty + 8 * p][tx] =
          W[((size_t)h * CC + ct * 32 + ty + 8 * p) * DH + dt * 32 + tx];
    __syncthreads();
#pragma unroll
    for (int p = 0; p < 4; ++p) {
      int n = sec * 1024 + h * 64 + dt * 32 + ty + 8 * p;
      Wt[(size_t)n * CC + ct * 32 + tx] = f2bf(T[tx][ty + 8 * p]);
    }
  } else {
    int i = ((bid - 11264) * 256 + tid) * 4;
    float4 f = *(const float4*)(Wo + i);
    uint2 o = {pk2(f.x, f.y), pk2(f.z, f.w)};
    *(uint2*)(Wob + i) = o;
  }
}

// ---------------------------------------------------------------------------
// QKV GEMM, phase-locked pipeline (measured equal to coarse variant).
// ---------------------------------------------------------------------------
__global__ __launch_bounds__(512, 2) void gemm_qkv(
    const u16* __restrict__ A, const u16* __restrict__ Bt,
    u16* __restrict__ qout, u16* __restrict__ kout, u16* __restrict__ vout) {
  __shared__ u16 As[3 * 128 * 32];  // 24 KB, slot stride 4096 elems
  __shared__ u16 Bs[3 * 384 * 32];  // 72 KB, slot stride 12288 elems

  int tid = threadIdx.x;
  int lane = tid & 63, w = tid >> 6;
  int wr = w >> 2, wc = w & 3;
  int g = lane >> 4, c = lane & 15;
  int m0 = blockIdx.y * 128, n0 = blockIdx.x * 384;

  floatx4 acc[4][6];
#pragma unroll
  for (int i = 0; i < 4; ++i)
#pragma unroll
    for (int j = 0; j < 6; ++j) acc[i][j] = (floatx4){0.f, 0.f, 0.f, 0.f};

  int arow = tid >> 2, acol = (tid & 3) * 8;
  const u16* Ag = A + (size_t)(m0 + arow) * CC + acol;
  const u16* Bg = Bt + (size_t)(n0 + arow) * CC + acol;
  u16* asd = As + tid * 8;
  u16* bsd = Bs + tid * 8;

  int aro = (wr * 64 + c) * 32 + g * 8;   // + mt*512
  int bro = (wc * 96 + c) * 32 + g * 8;   // + nt*512

  // prologue: stage tile 0 -> slot 0, tile 1 -> slot 1
  gload_lds16(Ag, asd);
  gload_lds16(Bg, bsd);
  gload_lds16(Bg + (size_t)128 * CC, bsd + 4096);
  gload_lds16(Bg + (size_t)256 * CC, bsd + 8192);
  gload_lds16(Ag + 32, asd + 4096);
  gload_lds16(Bg + 32, bsd + 12288);
  gload_lds16(Bg + 32 + (size_t)128 * CC, bsd + 12288 + 4096);
  gload_lds16(Bg + 32 + (size_t)256 * CC, bsd + 12288 + 8192);
  asm volatile("s_waitcnt vmcnt(4)" ::: "memory");  // tile 0 resident
  BAR();

#define QTILE(SCA, SCB, SPA, SPB, T2, STG, VMW)                               \
  {                                                                           \
    short8 af0 = *(const short8*)(As + (SCA) + aro);                          \
    short8 af1 = *(const short8*)(As + (SCA) + aro + 512);                    \
    short8 af2 = *(const short8*)(As + (SCA) + aro + 1024);                   \
    short8 af3 = *(const short8*)(As + (SCA) + aro + 1536);                   \
    short8 bv0 = *(const short8*)(Bs + (SCB) + bro);                          \
    short8 bv1 = *(const short8*)(Bs + (SCB) + bro + 512);                    \
    short8 bv2 = *(const short8*)(Bs + (SCB) + bro + 1024);                   \
    if (STG) {                                                                \
      gload_lds16(Ag + (size_t)(T2) * 32, asd + (SPA));                       \
      gload_lds16(Bg + (size_t)(T2) * 32, bsd + (SPB));                       \
    }                                                                         \
    BAR();                                                                    \
    __builtin_amdgcn_s_setprio(1);                                            \
    acc[0][0] = MFMA_BF16(af0, bv0, acc[0][0], 0, 0, 0);                      \
    acc[0][1] = MFMA_BF16(af0, bv1, acc[0][1], 0, 0, 0);                      \
    acc[0][2] = MFMA_BF16(af0, bv2, acc[0][2], 0, 0, 0);                      \
    acc[1][0] = MFMA_BF16(af1, bv0, acc[1][0], 0, 0, 0);                      \
    acc[1][1] = MFMA_BF16(af1, bv1, acc[1][1], 0, 0, 0);                      \
    acc[1][2] = MFMA_BF16(af1, bv2, acc[1][2], 0, 0, 0);                      \
    acc[2][0] = MFMA_BF16(af2, bv0, acc[2][0], 0, 0, 0);                      \
    acc[2][1] = MFMA_BF16(af2, bv1, acc[2][1], 0, 0, 0);                      \
    acc[2][2] = MFMA_BF16(af2, bv2, acc[2][2], 0, 0, 0);                      \
    acc[3][0] = MFMA_BF16(af3, bv0, acc[3][0], 0, 0, 0);                      \
    acc[3][1] = MFMA_BF16(af3, bv1, acc[3][1], 0, 0, 0);                      \
    acc[3][2] = MFMA_BF16(af3, bv2, acc[3][2], 0, 0, 0);                      \
    __builtin_amdgcn_s_setprio(0);                                            \
    BAR();                                                                    \
    short8 bv3 = *(const short8*)(Bs + (SCB) + bro + 1536);                   \
    short8 bv4 = *(const short8*)(Bs + (SCB) + bro + 2048);                   \
    short8 bv5 = *(const short8*)(Bs + (SCB) + bro + 2560);                   \
    if (STG) {                                                                \
      gload_lds16(Bg + (size_t)(T2) * 32 + (size_t)128 * CC,                  \
                  bsd + (SPB) + 4096);                                        \
      gload_lds16(Bg + (size_t)(T2) * 32 + (size_t)256 * CC,                  \
                  bsd + (SPB) + 8192);                                        \
    }                                                                         \
    BAR();                                                                    \
    __builtin_amdgcn_s_setprio(1);                                            \
    acc[0][3] = MFMA_BF16(af0, bv3, acc[0][3], 0, 0, 0);                      \
    acc[0][4] = MFMA_BF16(af0, bv4, acc[0][4], 0, 0, 0);                      \
    acc[0][5] = MFMA_BF16(af0, bv5, acc[0][5], 0, 0, 0);                      \
    acc[1][3] = MFMA_BF16(af1, bv3, acc[1][3], 0, 0, 0);                      \
    acc[1][4] = MFMA_BF16(af1, bv4, acc[1][4], 0, 0, 0);                      \
    acc[1][5] = MFMA_BF16(af1, bv5, acc[1][5], 0, 0, 0);                      \
    acc[2][3] = MFMA_BF16(af2, bv3, acc[2][3], 0, 0, 0);                      \
    acc[2][4] = MFMA_BF16(af2, bv4, acc[2][4], 0, 0, 0);                      \
    acc[2][5] = MFMA_BF16(af2, bv5, acc[2][5], 0, 0, 0);                      \
    acc[3][3] = MFMA_BF16(af3, bv3, acc[3][3], 0, 0, 0);                      \
    acc[3][4] = MFMA_BF16(af3, bv4, acc[3][4], 0, 0, 0);                      \
    acc[3][5] = MFMA_BF16(af3, bv5, acc[3][5], 0, 0, 0);                      \
    __builtin_amdgcn_s_setprio(0);                                            \
    VMW;                                                                      \
    BAR();                                                                    \
  }

  int scA = 0, snA = 4096, spA = 8192;
  int scB = 0, snB = 12288, spB = 24576;
#pragma unroll 1
  for (int t = 0; t < 30; ++t) {
    QTILE(scA, scB, spA, spB, t + 2, 1,
          asm volatile("s_waitcnt vmcnt(4)" ::: "memory"));
    int ta = scA; scA = snA; snA = spA; spA = ta;
    int tb = scB; scB = snB; snB = spB; spB = tb;
  }
  QTILE(scA, scB, spA, spB, 0, 0,
        asm volatile("s_waitcnt vmcnt(0)" ::: "memory"));
  {
    int ta = scA; scA = snA; snA = spA; spA = ta;
    int tb = scB; scB = snB; snB = spB; spB = tb;
  }
  QTILE(scA, scB, spA, spB, 0, 0, (void)0);
#undef QTILE

  // epilogue: scatter to q/k/v in [bh][t][d] layout (16-lane d-contiguous)
  int mrow = m0 + wr * 64 + g * 4;
  int ncol = n0 + wc * 96 + c;
#pragma unroll
  for (int nt = 0; nt < 6; ++nt) {
    int n = ncol + nt * 16;
    int sec = n >> 10, h = (n >> 6) & 15, d = n & 63;
    u16* dst = (sec == 0) ? qout : (sec == 1) ? kout : vout;
    float sc = (sec == 0) ? 0.18033688011112042f : 1.f;
    // ^ DH^-0.5 * log2(e): softmax runs in exp2 domain
#pragma unroll
    for (int mt = 0; mt < 4; ++mt) {
#pragma unroll
      for (int r = 0; r < 4; ++r) {
        int m = mrow + mt * 16 + r;
        int b = m >> 11, t = m & 2047;
        dst[(((size_t)(b * HH + h)) * TT + t) * DH + d] =
            f2bf(acc[mt][nt][r] * sc);
      }
    }
  }
}

// ---------------------------------------------------------------------------
// Output-projection GEMM: out[8192,1024] = Ow[8192,1024] @ Wob[1024,1024]^T
// + bias, fp32 out.  Port of the PROVEN gemm_qkv schedule (round-2: ~660 TF
// vs m97's 557): BM=128 BN=256 BK=32, 512 thr = 8 waves (2M x 4N), per-wave
// 64x64, acc[4][4].  Grid 4x64 = 256 blocks = exactly 1/CU, single round.
// Double-buffered LDS (48 KB); next tile's 3 global_load_lds issued BEFORE
// compute; ONE vmcnt(0)+barrier per K-tile -- loads aged a full iteration.
// ---------------------------------------------------------------------------
__global__ __launch_bounds__(512, 2) void gemm_out(
    const u16* __restrict__ A, const u16* __restrict__ Bt,
    float* __restrict__ out, const float* __restrict__ bias) {
  __shared__ u16 As[2 * 128 * 32];  // 16 KB, slot stride 4096 elems
  __shared__ u16 Bs[2 * 256 * 32];  // 32 KB, slot stride 8192 elems

  int tid = threadIdx.x;
  int lane = tid & 63, w = tid >> 6;
  int wr = w >> 2, wc = w & 3;
  int g = lane >> 4, c = lane & 15;
  int m0 = blockIdx.y * 128, n0 = blockIdx.x * 256;

  floatx4 acc[4][4];
#pragma unroll
  for (int i = 0; i < 4; ++i)
#pragma unroll
    for (int j = 0; j < 4; ++j) acc[i][j] = (floatx4){0.f, 0.f, 0.f, 0.f};

  int arow = tid >> 2, acol = (tid & 3) * 8;
  const u16* Ag = A + (size_t)(m0 + arow) * CC + acol;
  const u16* Bg = Bt + (size_t)(n0 + arow) * CC + acol;
  u16* asd = As + tid * 8;
  u16* bsd = Bs + tid * 8;

  int aro = (wr * 64 + c) * 32 + g * 8;   // + mt*512
  int bro = (wc * 64 + c) * 32 + g * 8;   // + nt*512

  // prologue: stage tile 0 into slot 0 (A: 1 load, B: 2 loads per thread set)
  gload_lds16(Ag, asd);
  gload_lds16(Bg, bsd);
  gload_lds16(Bg + (size_t)128 * CC, bsd + 4096);
  asm volatile("s_waitcnt vmcnt(0)" ::: "memory");
  BAR();

#define OTILE(p, t)                                                           \
  {                                                                           \
    if ((t) + 1 < 32) { /* stage tile t+1 into slot p^1 (freed last iter) */  \
      size_t ko = (size_t)((t) + 1) * 32;                                     \
      gload_lds16(Ag + ko, asd + ((p) ^ 1) * 4096);                           \
      gload_lds16(Bg + ko, bsd + ((p) ^ 1) * 8192);                           \
      gload_lds16(Bg + ko + (size_t)128 * CC, bsd + ((p) ^ 1) * 8192 + 4096); \
    }                                                                         \
    short8 bv[4];                                                             \
    _Pragma("unroll") for (int nt = 0; nt < 4; ++nt)                          \
        bv[nt] = *(const short8*)(Bs + (p) * 8192 + bro + nt * 512);          \
    __builtin_amdgcn_s_setprio(1);                                            \
    _Pragma("unroll") for (int mt = 0; mt < 4; ++mt) {                        \
      short8 af = *(const short8*)(As + (p) * 4096 + aro + mt * 512);         \
      _Pragma("unroll") for (int nt = 0; nt < 4; ++nt)                        \
          acc[mt][nt] = MFMA_BF16(af, bv[nt], acc[mt][nt], 0, 0, 0);          \
    }                                                                         \
    __builtin_amdgcn_s_setprio(0);                                            \
    asm volatile("s_waitcnt vmcnt(0)" ::: "memory"); /* aged a full iter */   \
    BAR();                                                                    \
  }

#pragma unroll 1
  for (int tt = 0; tt < 16; ++tt) {
    OTILE(0, 2 * tt);
    OTILE(1, 2 * tt + 1);
  }
#undef OTILE

  // epilogue: out[m][n] = acc + bias[n], fp32, 16-lane n-contiguous
  int mrow = m0 + wr * 64 + g * 4;
  int ncol = n0 + wc * 64 + c;
#pragma unroll
  for (int nt = 0; nt < 4; ++nt) {
    int n = ncol + nt * 16;
    float bn = bias[n];
#pragma unroll
    for (int mt = 0; mt < 4; ++mt) {
#pragma unroll
      for (int r = 0; r < 4; ++r) {
        int m = mrow + mt * 16 + r;
        out[(size_t)m * CC + n] = acc[mt][nt][r] + bn;
      }
    }
  }
}

// ---------------------------------------------------------------------------
// V permute-transpose: v[bh][s][d] -> vP[bh][d][tile][u] where
// s = tile*64 + (u&3)*16 + (u>>2)  (i.e. u = 4*(s&15) + ((s>>4)&3)).
// ---------------------------------------------------------------------------
__global__ __launch_bounds__(256) void vtrans(const u16* __restrict__ v,
                                              u16* __restrict__ vP) {
  __shared__ u16 Ld[64][72];
  int tile = blockIdx.x, bh = blockIdx.y, tid = threadIdx.x;
  int row = tid >> 2, col = (tid & 3) * 16;
  const u16* src = v + ((size_t)bh * TT + tile * 64 + row) * DH + col;
  *(uint4*)(&Ld[row][col]) = *(const uint4*)(src);
  *(uint4*)(&Ld[row][col + 8]) = *(const uint4*)(src + 8);
  __syncthreads();
  int d = tid >> 2, u0 = (tid & 3) * 16;
  union { u16 h[16]; uint4 q[2]; } o;
#pragma unroll
  for (int k = 0; k < 16; ++k) {
    int u = u0 + k;
    int s = ((u & 3) << 4) | (u >> 2);
    o.h[k] = Ld[s][d];
  }
  u16* dst = vP + ((size_t)(bh * DH + d)) * TT + tile * 64 + u0;
  *(uint4*)(dst) = o.q[0];
  *(uint4*)(dst + 8) = o.q[1];
}

// ---------------------------------------------------------------------------
// Causal flash, round-7 proven structure: padded-72 LDS, setprio clusters,
// pre-barrier prefetch, separate merge_heavy kernel.  Round-8 lesson
// recorded: in-kernel cross-block merge needs device-scope __threadfence,
// which on CDNA4 (non-coherent per-XCD L2) forces an L2 writeback per
// producer block -- 512 flushes destroyed K/V caching (78 -> 300 us).
// A 9-us separate merge kernel is the cheap form of cross-block handoff.
// LPT chunking: heavy q-tiles split into two key-halves; scale-free softmax
// partials merge by plain addition in merge_heavy.
// ---------------------------------------------------------------------------
__constant__ unsigned char CHUNK_X[24] = {15, 15, 7, 14, 14, 13, 13, 6,
                                          12, 12, 11, 11, 5, 10, 10, 9,
                                          9,  4,  8,  8,  3, 2,  1,  0};
__constant__ unsigned char CHUNK_H[24] = {0, 1, 2, 0, 1, 0, 1, 2, 0, 1, 0, 1,
                                          2, 0, 1, 0, 1, 2, 0, 1, 2, 2, 2, 2};

__global__ __launch_bounds__(256, 4) void flash_attn(
    const u16* __restrict__ q, const u16* __restrict__ k,
    const u16* __restrict__ vP, u16* __restrict__ O,
    float* __restrict__ opart, float* __restrict__ lpart) {
  __shared__ u16 Ks[64][72];     // [s][d]
  __shared__ u16 Vs[64][72];     // [d][u]  (u = permuted s)
  __shared__ u16 Ps[4][32][72];  // per-wave P tile [m][u]

  int tid = threadIdx.x;
  int lane = tid & 63, w = tid >> 6;
  int g = lane >> 4, c = lane & 15;

  int id = blockIdx.x;
  int e = id >> 6, bh = id & 63;
  int x = CHUNK_X[e], hf = CHUNK_H[e];  // hf: 0/1 = key-half, 2 = whole tile
  int sb, se;
  if (hf == 2) {
    sb = 0; se = 2 * x + 2;
  } else {
    int n = x + 1; sb = hf * n; se = sb + n;
  }
  int t0 = x << 7;

  const u16* qb = q + (size_t)bh * TT * DH;
  const u16* kb = k + (size_t)bh * TT * DH;
  const u16* vb = vP + (size_t)bh * DH * TT;

  // Q fragments persistent in registers (A-layout: m=lane&15, k=(lane>>4)*8+j)
  short8 qf[2][2];
#pragma unroll
  for (int mt = 0; mt < 2; ++mt) {
    int qrow = t0 + w * 32 + mt * 16 + c;
#pragma unroll
    for (int kc = 0; kc < 2; ++kc)
      qf[mt][kc] = *(const short8*)(qb + (size_t)qrow * DH + kc * 32 + g * 8);
  }

  const floatx4 zf = {0.f, 0.f, 0.f, 0.f};
  const short8 onesf = {(short)0x3F80, (short)0x3F80, (short)0x3F80,
                        (short)0x3F80, (short)0x3F80, (short)0x3F80,
                        (short)0x3F80, (short)0x3F80};  // bf16 1.0 x8

  floatx4 oacc[2][4];
#pragma unroll
  for (int mt = 0; mt < 2; ++mt)
#pragma unroll
    for (int nt = 0; nt < 4; ++nt) oacc[mt][nt] = zf;
  floatx4 lacc[2];
  lacc[0] = zf;
  lacc[1] = zf;

  // staging: row = tid>>2 (0..63), col base = (tid&3)*16, 2x16B per tensor
  int srow = tid >> 2, scol = (tid & 3) * 16;
  const u16* kbase = kb + (size_t)srow * DH + scol;
  const u16* vbase = vb + (size_t)srow * TT + scol;  // vP rows: [d][t-contig]

  // preload iter sb
  uint4 kr0 = *(const uint4*)(kbase + (size_t)(sb << 6) * DH);
  uint4 kr1 = *(const uint4*)(kbase + (size_t)(sb << 6) * DH + 8);
  uint4 vr0 = *(const uint4*)(vbase + (sb << 6));
  uint4 vr1 = *(const uint4*)(vbase + (sb << 6) + 8);

  int nfull = 2 * x;  // iters >= nfull need the causal mask
  int wmax = t0 + w * 32 + 31;
  for (int it = sb; it < se; ++it) {
    int s0 = it << 6;
    __syncthreads();  // all waves done reading prev tiles
    *(uint4*)(&Ks[srow][scol]) = kr0;
    *(uint4*)(&Ks[srow][scol + 8]) = kr1;
    *(uint4*)(&Vs[srow][scol]) = vr0;
    *(uint4*)(&Vs[srow][scol + 8]) = vr1;
    if (it + 1 < se) {  // prefetch issued BEFORE barrier: regs already
      size_t koff = (size_t)((it + 1) << 6) * DH;  // consumed by ds_writes
      int voff = (it + 1) << 6;
      kr0 = *(const uint4*)(kbase + koff);
      kr1 = *(const uint4*)(kbase + koff + 8);
      vr0 = *(const uint4*)(vbase + voff);
      vr1 = *(const uint4*)(vbase + voff + 8);
    }
    __syncthreads();
    if (s0 > wmax) continue;  // wave-uniform: tile fully masked (last iter)
    bool masked = (it >= nfull);

    // S = Q K^T ; kf shared across both m-tiles; kc=0 uses zero C-operand
    floatx4 z[2][4];
    __builtin_amdgcn_s_setprio(1);
#pragma unroll
    for (int n = 0; n < 4; ++n) {
      short8 kf = *(const short8*)(&Ks[n * 16 + c][g * 8]);
      z[0][n] = MFMA_BF16(qf[0][0], kf, zf, 0, 0, 0);
      z[1][n] = MFMA_BF16(qf[1][0], kf, zf, 0, 0, 0);
    }
#pragma unroll
    for (int n = 0; n < 4; ++n) {
      short8 kf = *(const short8*)(&Ks[n * 16 + c][32 + g * 8]);
      z[0][n] = MFMA_BF16(qf[0][1], kf, z[0][n], 0, 0, 0);
      z[1][n] = MFMA_BF16(qf[1][1], kf, z[1][n], 0, 0, 0);
    }
    __builtin_amdgcn_s_setprio(0);

    // softmax (no offset: uniform scale cancels in the final division);
    // P packed to bf16 by v_perm truncation, b64 stores
#pragma unroll
    for (int mt = 0; mt < 2; ++mt) {
      int qr = t0 + w * 32 + mt * 16 + g * 4;
#pragma unroll
      for (int r = 0; r < 4; ++r) {
        float p0 = exp2f(z[mt][0][r]);
        float p1 = exp2f(z[mt][1][r]);
        float p2 = exp2f(z[mt][2][r]);
        float p3 = exp2f(z[mt][3][r]);
        if (masked) {
          if (s0 + c > qr + r) p0 = 0.f;
          if (s0 + 16 + c > qr + r) p1 = 0.f;
          if (s0 + 32 + c > qr + r) p2 = 0.f;
          if (s0 + 48 + c > qr + r) p3 = 0.f;
        }
        // u-layout: s = n*16+c -> u = 4c+n; 4 values contiguous at u0=4c
        uint2 pk = {pktrunc(p0, p1), pktrunc(p2, p3)};
        *(uint2*)(&Ps[w][mt * 16 + g * 4 + r][4 * c]) = pk;
      }
    }

    // PV + lsum-by-MFMA: vf shared across both m-tiles (intra-wave LDS)
    __builtin_amdgcn_s_setprio(1);
#pragma unroll
    for (int kc = 0; kc < 2; ++kc) {
      short8 pf0 = *(const short8*)(&Ps[w][c][kc * 32 + g * 8]);
      short8 pf1 = *(const short8*)(&Ps[w][16 + c][kc * 32 + g * 8]);
      lacc[0] = MFMA_BF16(pf0, onesf, lacc[0], 0, 0, 0);
      lacc[1] = MFMA_BF16(pf1, onesf, lacc[1], 0, 0, 0);
#pragma unroll
      for (int nt = 0; nt < 4; ++nt) {
        short8 vf = *(const short8*)(&Vs[nt * 16 + c][kc * 32 + g * 8]);
        oacc[0][nt] = MFMA_BF16(pf0, vf, oacc[0][nt], 0, 0, 0);
        oacc[1][nt] = MFMA_BF16(pf1, vf, oacc[1][nt], 0, 0, 0);
      }
    }
    __builtin_amdgcn_s_setprio(0);
  }

  // epilogue: lacc[mt][r] already holds the full row-sum (replicated over c)
  int b = bh >> 4, h = bh & 15;
  if (hf == 2) {
    // light chunk: normalize and write bf16 directly
#pragma unroll
    for (int mt = 0; mt < 2; ++mt) {
      float inv[4];
#pragma unroll
      for (int r = 0; r < 4; ++r) inv[r] = 1.f / lacc[mt][r];
#pragma unroll
      for (int nt = 0; nt < 4; ++nt)
#pragma unroll
        for (int r = 0; r < 4; ++r) {
          int trow = t0 + w * 32 + mt * 16 + g * 4 + r;
          O[((size_t)b * TT + trow) * CC + h * DH + nt * 16 + c] =
              f2bf(oacc[mt][nt][r] * inv[r]);
        }
    }
  } else {
    // heavy half: store raw fp32 partials; merge_heavy combines
    float* os = opart + ((size_t)hf * 65536 + (size_t)bh * 1024) * 64;
    float* ls = lpart + (size_t)hf * 65536 + (size_t)bh * 1024;
#pragma unroll
    for (int mt = 0; mt < 2; ++mt) {
      int r0 = t0 - 1024 + w * 32 + mt * 16 + g * 4;  // local heavy-row base
#pragma unroll
      for (int nt = 0; nt < 4; ++nt)
#pragma unroll
        for (int r = 0; r < 4; ++r)
          os[(size_t)(r0 + r) * 64 + nt * 16 + c] = oacc[mt][nt][r];
      if (c == 0)
#pragma unroll
        for (int r = 0; r < 4; ++r) ls[r0 + r] = lacc[mt][r];
    }
  }
}

// ---------------------------------------------------------------------------
// Merge the two key-half partials for heavy rows (t in [1024, 2048)):
// Ow = (o0 + o1) / (l0 + l1). ~42 MB traffic, memory-bound.
// ---------------------------------------------------------------------------
__global__ __launch_bounds__(256) void merge_heavy(
    const float* __restrict__ op, const float* __restrict__ lp,
    u16* __restrict__ O) {
  int gid = blockIdx.x * 256 + threadIdx.x;  // 64 bh * 1024 rows * 16 chunks
  int dq = gid & 15;                         // float4 chunk within d=64
  int row = gid >> 4;                        // bh*1024 + lr
  float4 a = *(const float4*)(op + (size_t)row * 64 + dq * 4);
  float4 b = *(const float4*)(op + ((size_t)row + 65536) * 64 + dq * 4);
  float inv = 1.f / (lp[row] + lp[row + 65536]);
  int bh = row >> 10, lr = row & 1023;
  int bb = bh >> 4, h = bh & 15;
  u16* dst = O + ((size_t)bb * TT + 1024 + lr) * CC + h * DH + dq * 4;
  uint2 o = {pk2((a.x + b.x) * inv, (a.y + b.y) * inv),
             pk2((a.z + b.z) * inv, (a.w + b.w) * inv)};
  *(uint2*)dst = o;
}

// ---------------------------------------------------------------------------
extern "C" void kernel_launch(void* const* d_in, const int* in_sizes, int n_in,
                              void* d_out, int out_size, void* d_ws,
                              size_t ws_size, hipStream_t stream) {
  const float* x = (const float*)d_in[0];
  const float* Wq = (const float*)d_in[1];
  const float* Wk = (const float*)d_in[2];
  const float* Wv = (const float*)d_in[3];
  const float* Wo = (const float*)d_in[4];
  const float* bo = (const float*)d_in[5];
  float* out = (float*)d_out;

  u16* ws = (u16*)d_ws;
  u16* xb = ws;                        // 8388608  (reused as Ow after QKV GEMM)
  u16* Wt = xb + 8388608;              // 3145728  (dead after gemm_qkv: lpart)
  u16* Wob = Wt + 3145728;             // 1048576
  u16* qw = Wob + 1048576;             // 8388608
  u16* kw = qw + 8388608;              // 8388608
  u16* vw = kw + 8388608;              // 8388608 ([bh][t][d], coalesced)
  u16* vP = vw + 8388608;              // 8388608 (permuted [bh][d][tile][u])
  u16* Ow = xb;                        // alias: xb dead after gemm_qkv
  float* opart = (float*)d_out;        // dead until gemm_out
  float* lpart = (float*)Wt;           // Wt dead after gemm_qkv

  convert_kernel<<<12288, 256, 0, stream>>>(x, Wq, Wk, Wv, Wo, xb, Wt, Wob);

  gemm_qkv<<<dim3(NQKV / 384, MM / 128), 512, 0, stream>>>(
      xb, Wt, qw, kw, vw);

  vtrans<<<dim3(TT / 64, BB * HH), 256, 0, stream>>>(vw, vP);

  flash_attn<<<dim3(1536), 256, 0, stream>>>(qw, kw, vP, Ow, opart, lpart);

  merge_heavy<<<dim3(4096), 256, 0, stream>>>(opart, lpart, Ow);

  gemm_out<<<dim3(CC / 256, MM / 128), 512, 0, stream>>>(Ow, Wob, out, bo);
}

// Round 10
// 276.052 us; speedup vs baseline: 1.7867x; 1.0239x over previous
//
#include <hip/hip_runtime.h>
#include <stdint.h>

typedef unsigned short u16;
typedef __attribute__((ext_vector_type(8))) short short8;
typedef __attribute__((ext_vector_type(4))) float floatx4;

#define MFMA_BF16 __builtin_amdgcn_mfma_f32_16x16x32_bf16

// dims
#define BB 4
#define TT 2048
#define CC 1024
#define HH 16
#define DH 64
#define MM (BB * TT)      // 8192
#define NQKV (3 * CC)     // 3072

__device__ __forceinline__ u16 f2bf(float f) {
  union { float f; uint32_t u; } un;
  un.f = f;
  uint32_t u = un.u;
  u += 0x7fffu + ((u >> 16) & 1u);   // round-to-nearest-even
  return (u16)(u >> 16);
}

__device__ __forceinline__ uint32_t pk2(float a, float b) {
  return (uint32_t)f2bf(a) | ((uint32_t)f2bf(b) << 16);
}

// pack hi16(a) | hi16(b)<<16 in ONE v_perm_b32 (truncating bf16 round)
__device__ __forceinline__ uint32_t pktrunc(float a, float b) {
  union { float f; uint32_t u; } ua, ub;
  ua.f = a; ub.f = b;
  return __builtin_amdgcn_perm(ub.u, ua.u, 0x07060302u);
}

// async global->LDS, 16B per lane. lds dst = wave-uniform base + lane*16.
__device__ __forceinline__ void gload_lds16(const u16* g, u16* l) {
  __builtin_amdgcn_global_load_lds(
      (const __attribute__((address_space(1))) unsigned int*)g,
      (__attribute__((address_space(3))) unsigned int*)l, 16, 0, 0);
}

// raw barrier with compiler-level memory fence (no vmcnt/lgkm drain)
__device__ __forceinline__ void BAR() {
  asm volatile("" ::: "memory");
  __builtin_amdgcn_s_barrier();
  asm volatile("" ::: "memory");
}

// ---------------------------------------------------------------------------
// Kernel 0: fp32 -> bf16 conversions + coalesced weight transpose.
// ---------------------------------------------------------------------------
__global__ __launch_bounds__(256) void convert_kernel(
    const float* __restrict__ x, const float* __restrict__ Wq,
    const float* __restrict__ Wk, const float* __restrict__ Wv,
    const float* __restrict__ Wo, u16* __restrict__ xb,
    u16* __restrict__ Wt, u16* __restrict__ Wob) {
  __shared__ float T[32][33];
  int bid = blockIdx.x, tid = threadIdx.x;
  if (bid < 8192) {
    int i = (bid * 256 + tid) * 4;
    float4 f = *(const float4*)(x + i);
    uint2 o = {pk2(f.x, f.y), pk2(f.z, f.w)};
    *(uint2*)(xb + i) = o;
  } else if (bid < 8192 + 3072) {
    int tb = bid - 8192;
    int sec = tb >> 10, rem = tb & 1023;
    int h = rem >> 6, sub = rem & 63, ct = sub >> 1, dt = sub & 1;
    const float* W = (sec == 0) ? Wq : (sec == 1) ? Wk : Wv;
    int tx = tid & 31, ty = tid >> 5;
#pragma unroll
    for (int p = 0; p < 4; ++p)
      T[ty + 8 * p][tx] =
          W[((size_t)h * CC + ct * 32 + ty + 8 * p) * DH + dt * 32 + tx];
    __syncthreads();
#pragma unroll
    for (int p = 0; p < 4; ++p) {
      int n = sec * 1024 + h * 64 + dt * 32 + ty + 8 * p;
      Wt[(size_t)n * CC + ct * 32 + tx] = f2bf(T[tx][ty + 8 * p]);
    }
  } else {
    int i = ((bid - 11264) * 256 + tid) * 4;
    float4 f = *(const float4*)(Wo + i);
    uint2 o = {pk2(f.x, f.y), pk2(f.z, f.w)};
    *(uint2*)(Wob + i) = o;
  }
}

// ---------------------------------------------------------------------------
// QKV GEMM, phase-locked pipeline (measured equal to coarse variant).
// ---------------------------------------------------------------------------
__global__ __launch_bounds__(512, 2) void gemm_qkv(
    const u16* __restrict__ A, const u16* __restrict__ Bt,
    u16* __restrict__ qout, u16* __restrict__ kout, u16* __restrict__ vout) {
  __shared__ u16 As[3 * 128 * 32];  // 24 KB, slot stride 4096 elems
  __shared__ u16 Bs[3 * 384 * 32];  // 72 KB, slot stride 12288 elems

  int tid = threadIdx.x;
  int lane = tid & 63, w = tid >> 6;
  int wr = w >> 2, wc = w & 3;
  int g = lane >> 4, c = lane & 15;
  int m0 = blockIdx.y * 128, n0 = blockIdx.x * 384;

  floatx4 acc[4][6];
#pragma unroll
  for (int i = 0; i < 4; ++i)
#pragma unroll
    for (int j = 0; j < 6; ++j) acc[i][j] = (floatx4){0.f, 0.f, 0.f, 0.f};

  int arow = tid >> 2, acol = (tid & 3) * 8;
  const u16* Ag = A + (size_t)(m0 + arow) * CC + acol;
  const u16* Bg = Bt + (size_t)(n0 + arow) * CC + acol;
  u16* asd = As + tid * 8;
  u16* bsd = Bs + tid * 8;

  int aro = (wr * 64 + c) * 32 + g * 8;   // + mt*512
  int bro = (wc * 96 + c) * 32 + g * 8;   // + nt*512

  // prologue: stage tile 0 -> slot 0, tile 1 -> slot 1
  gload_lds16(Ag, asd);
  gload_lds16(Bg, bsd);
  gload_lds16(Bg + (size_t)128 * CC, bsd + 4096);
  gload_lds16(Bg + (size_t)256 * CC, bsd + 8192);
  gload_lds16(Ag + 32, asd + 4096);
  gload_lds16(Bg + 32, bsd + 12288);
  gload_lds16(Bg + 32 + (size_t)128 * CC, bsd + 12288 + 4096);
  gload_lds16(Bg + 32 + (size_t)256 * CC, bsd + 12288 + 8192);
  asm volatile("s_waitcnt vmcnt(4)" ::: "memory");  // tile 0 resident
  BAR();

#define QTILE(SCA, SCB, SPA, SPB, T2, STG, VMW)                               \
  {                                                                           \
    short8 af0 = *(const short8*)(As + (SCA) + aro);                          \
    short8 af1 = *(const short8*)(As + (SCA) + aro + 512);                    \
    short8 af2 = *(const short8*)(As + (SCA) + aro + 1024);                   \
    short8 af3 = *(const short8*)(As + (SCA) + aro + 1536);                   \
    short8 bv0 = *(const short8*)(Bs + (SCB) + bro);                          \
    short8 bv1 = *(const short8*)(Bs + (SCB) + bro + 512);                    \
    short8 bv2 = *(const short8*)(Bs + (SCB) + bro + 1024);                   \
    if (STG) {                                                                \
      gload_lds16(Ag + (size_t)(T2) * 32, asd + (SPA));                       \
      gload_lds16(Bg + (size_t)(T2) * 32, bsd + (SPB));                       \
    }                                                                         \
    BAR();                                                                    \
    __builtin_amdgcn_s_setprio(1);                                            \
    acc[0][0] = MFMA_BF16(af0, bv0, acc[0][0], 0, 0, 0);                      \
    acc[0][1] = MFMA_BF16(af0, bv1, acc[0][1], 0, 0, 0);                      \
    acc[0][2] = MFMA_BF16(af0, bv2, acc[0][2], 0, 0, 0);                      \
    acc[1][0] = MFMA_BF16(af1, bv0, acc[1][0], 0, 0, 0);                      \
    acc[1][1] = MFMA_BF16(af1, bv1, acc[1][1], 0, 0, 0);                      \
    acc[1][2] = MFMA_BF16(af1, bv2, acc[1][2], 0, 0, 0);                      \
    acc[2][0] = MFMA_BF16(af2, bv0, acc[2][0], 0, 0, 0);                      \
    acc[2][1] = MFMA_BF16(af2, bv1, acc[2][1], 0, 0, 0);                      \
    acc[2][2] = MFMA_BF16(af2, bv2, acc[2][2], 0, 0, 0);                      \
    acc[3][0] = MFMA_BF16(af3, bv0, acc[3][0], 0, 0, 0);                      \
    acc[3][1] = MFMA_BF16(af3, bv1, acc[3][1], 0, 0, 0);                      \
    acc[3][2] = MFMA_BF16(af3, bv2, acc[3][2], 0, 0, 0);                      \
    __builtin_amdgcn_s_setprio(0);                                            \
    BAR();                                                                    \
    short8 bv3 = *(const short8*)(Bs + (SCB) + bro + 1536);                   \
    short8 bv4 = *(const short8*)(Bs + (SCB) + bro + 2048);                   \
    short8 bv5 = *(const short8*)(Bs + (SCB) + bro + 2560);                   \
    if (STG) {                                                                \
      gload_lds16(Bg + (size_t)(T2) * 32 + (size_t)128 * CC,                  \
                  bsd + (SPB) + 4096);                                        \
      gload_lds16(Bg + (size_t)(T2) * 32 + (size_t)256 * CC,                  \
                  bsd + (SPB) + 8192);                                        \
    }                                                                         \
    BAR();                                                                    \
    __builtin_amdgcn_s_setprio(1);                                            \
    acc[0][3] = MFMA_BF16(af0, bv3, acc[0][3], 0, 0, 0);                      \
    acc[0][4] = MFMA_BF16(af0, bv4, acc[0][4], 0, 0, 0);                      \
    acc[0][5] = MFMA_BF16(af0, bv5, acc[0][5], 0, 0, 0);                      \
    acc[1][3] = MFMA_BF16(af1, bv3, acc[1][3], 0, 0, 0);                      \
    acc[1][4] = MFMA_BF16(af1, bv4, acc[1][4], 0, 0, 0);                      \
    acc[1][5] = MFMA_BF16(af1, bv5, acc[1][5], 0, 0, 0);                      \
    acc[2][3] = MFMA_BF16(af2, bv3, acc[2][3], 0, 0, 0);                      \
    acc[2][4] = MFMA_BF16(af2, bv4, acc[2][4], 0, 0, 0);                      \
    acc[2][5] = MFMA_BF16(af2, bv5, acc[2][5], 0, 0, 0);                      \
    acc[3][3] = MFMA_BF16(af3, bv3, acc[3][3], 0, 0, 0);                      \
    acc[3][4] = MFMA_BF16(af3, bv4, acc[3][4], 0, 0, 0);                      \
    acc[3][5] = MFMA_BF16(af3, bv5, acc[3][5], 0, 0, 0);                      \
    __builtin_amdgcn_s_setprio(0);                                            \
    VMW;                                                                      \
    BAR();                                                                    \
  }

  int scA = 0, snA = 4096, spA = 8192;
  int scB = 0, snB = 12288, spB = 24576;
#pragma unroll 1
  for (int t = 0; t < 30; ++t) {
    QTILE(scA, scB, spA, spB, t + 2, 1,
          asm volatile("s_waitcnt vmcnt(4)" ::: "memory"));
    int ta = scA; scA = snA; snA = spA; spA = ta;
    int tb = scB; scB = snB; snB = spB; spB = tb;
  }
  QTILE(scA, scB, spA, spB, 0, 0,
        asm volatile("s_waitcnt vmcnt(0)" ::: "memory"));
  {
    int ta = scA; scA = snA; snA = spA; spA = ta;
    int tb = scB; scB = snB; snB = spB; spB = tb;
  }
  QTILE(scA, scB, spA, spB, 0, 0, (void)0);
#undef QTILE

  // epilogue: scatter to q/k/v in [bh][t][d] layout (16-lane d-contiguous)
  int mrow = m0 + wr * 64 + g * 4;
  int ncol = n0 + wc * 96 + c;
#pragma unroll
  for (int nt = 0; nt < 6; ++nt) {
    int n = ncol + nt * 16;
    int sec = n >> 10, h = (n >> 6) & 15, d = n & 63;
    u16* dst = (sec == 0) ? qout : (sec == 1) ? kout : vout;
    float sc = (sec == 0) ? 0.18033688011112042f : 1.f;
    // ^ DH^-0.5 * log2(e): softmax runs in exp2 domain
#pragma unroll
    for (int mt = 0; mt < 4; ++mt) {
#pragma unroll
      for (int r = 0; r < 4; ++r) {
        int m = mrow + mt * 16 + r;
        int b = m >> 11, t = m & 2047;
        dst[(((size_t)(b * HH + h)) * TT + t) * DH + d] =
            f2bf(acc[mt][nt][r] * sc);
      }
    }
  }
}

// ---------------------------------------------------------------------------
// GEMM: C[M,N] = A[M,K] @ Bt[N,K]^T, bf16 in, fp32 accum. m97 pattern.
// Used as MODE 1 (output projection +bias fp32).  Round-9 lesson: the
// 8-wave aged-vmcnt port (BN=256, 1 block/CU single round) was ~5 us
// SLOWER at this shape -- m97's 256-thr/2-blocks-per-CU overlap wins when
// the N-panel is narrow.  Keep this proven kernel.
// ---------------------------------------------------------------------------
template <int MODE>
__global__ __launch_bounds__(256) void gemm_bt(
    const u16* __restrict__ A, const u16* __restrict__ Bt, int M, int N, int K,
    u16* __restrict__ qout, u16* __restrict__ kout, u16* __restrict__ vout,
    float* __restrict__ out, const float* __restrict__ bias) {
  __shared__ u16 As[128][64];  // unpadded: required by global_load_lds
  __shared__ u16 Bs[128][64];
  int tid = threadIdx.x;
  int lane = tid & 63, w = tid >> 6;
  int wm = w >> 1, wn = w & 1;
  int g = lane >> 4, c = lane & 15;
  int m0 = blockIdx.y * 128, n0 = blockIdx.x * 128;

  floatx4 acc[4][4];
#pragma unroll
  for (int i = 0; i < 4; ++i)
#pragma unroll
    for (int j = 0; j < 4; ++j) acc[i][j] = (floatx4){0.f, 0.f, 0.f, 0.f};

  int srow = 32 * w + (lane >> 3);
  int scol = (lane & 7) * 8;
  const u16* Ag = A + (size_t)(m0 + srow) * K + scol;
  const u16* Bg = Bt + (size_t)(n0 + srow) * K + scol;
  u16* AsB = &As[32 * w][0];
  u16* BsB = &Bs[32 * w][0];

  for (int k0 = 0; k0 < K; k0 += 64) {
    __syncthreads();
#pragma unroll
    for (int j = 0; j < 4; ++j)
      gload_lds16(Ag + k0 + (size_t)j * 8 * K, AsB + j * 512);
#pragma unroll
    for (int j = 0; j < 4; ++j)
      gload_lds16(Bg + k0 + (size_t)j * 8 * K, BsB + j * 512);
    __syncthreads();
#pragma unroll
    for (int kc = 0; kc < 2; ++kc) {
      short8 af[4], bfv[4];
#pragma unroll
      for (int mt = 0; mt < 4; ++mt)
        af[mt] = *(const short8*)(&As[wm * 64 + mt * 16 + c][kc * 32 + g * 8]);
#pragma unroll
      for (int nt = 0; nt < 4; ++nt)
        bfv[nt] = *(const short8*)(&Bs[wn * 64 + nt * 16 + c][kc * 32 + g * 8]);
#pragma unroll
      for (int mt = 0; mt < 4; ++mt)
#pragma unroll
        for (int nt = 0; nt < 4; ++nt)
          acc[mt][nt] = MFMA_BF16(af[mt], bfv[nt], acc[mt][nt], 0, 0, 0);
    }
  }

#pragma unroll
  for (int mt = 0; mt < 4; ++mt) {
#pragma unroll
    for (int nt = 0; nt < 4; ++nt) {
#pragma unroll
      for (int r = 0; r < 4; ++r) {
        int m = m0 + wm * 64 + mt * 16 + g * 4 + r;  // C-layout: row=(lane>>4)*4+reg
        int n = n0 + wn * 64 + nt * 16 + c;          //           col=lane&15
        float v = acc[mt][nt][r];
        if (MODE == 0) {
          int b = m >> 11, t = m & 2047;
          int sec = n >> 10, h = (n >> 6) & 15, d = n & 63;
          size_t idx = (((size_t)(b * HH + h)) * TT + t) * DH + d;
          if (sec == 0)
            qout[idx] = f2bf(v * 0.18033688011112042f);
          else if (sec == 1)
            kout[idx] = f2bf(v);
          else
            vout[idx] = f2bf(v);
        } else {
          out[(size_t)m * N + n] = v + bias[n];
        }
      }
    }
  }
}

// ---------------------------------------------------------------------------
// V permute-transpose: v[bh][s][d] -> vP[bh][d][tile][u] where
// s = tile*64 + (u&3)*16 + (u>>2)  (i.e. u = 4*(s&15) + ((s>>4)&3)).
// ---------------------------------------------------------------------------
__global__ __launch_bounds__(256) void vtrans(const u16* __restrict__ v,
                                              u16* __restrict__ vP) {
  __shared__ u16 Ld[64][72];
  int tile = blockIdx.x, bh = blockIdx.y, tid = threadIdx.x;
  int row = tid >> 2, col = (tid & 3) * 16;
  const u16* src = v + ((size_t)bh * TT + tile * 64 + row) * DH + col;
  *(uint4*)(&Ld[row][col]) = *(const uint4*)(src);
  *(uint4*)(&Ld[row][col + 8]) = *(const uint4*)(src + 8);
  __syncthreads();
  int d = tid >> 2, u0 = (tid & 3) * 16;
  union { u16 h[16]; uint4 q[2]; } o;
#pragma unroll
  for (int k = 0; k < 16; ++k) {
    int u = u0 + k;
    int s = ((u & 3) << 4) | (u >> 2);
    o.h[k] = Ld[s][d];
  }
  u16* dst = vP + ((size_t)(bh * DH + d)) * TT + tile * 64 + u0;
  *(uint4*)(dst) = o.q[0];
  *(uint4*)(dst + 8) = o.q[1];
}

// ---------------------------------------------------------------------------
// Causal flash, round-7 proven structure: padded-72 LDS, setprio clusters,
// pre-barrier prefetch, separate merge_heavy kernel.
// Session lessons encoded here:
//  * padded-72 LDS with benign ~2-way conflicts BEATS zero-conflict XOR
//    swizzle (round 6: swizzle cost 40% via addressing + L1 effects).
//  * launch_bounds min-waves arg caps VGPRs: (256,5) spilled (round 5).
//  * LDS-shared K/V staging BEATS per-wave direct global loads (round 4:
//    4x L2 traffic, 81 -> 147 us).
//  * cross-block in-kernel merge needs device __threadfence = per-block L2
//    writeback on CDNA4 -> separate merge kernel is cheaper (round 8).
// LPT chunking: heavy q-tiles split into two key-halves; scale-free softmax
// partials merge by plain addition in merge_heavy.
// ---------------------------------------------------------------------------
__constant__ unsigned char CHUNK_X[24] = {15, 15, 7, 14, 14, 13, 13, 6,
                                          12, 12, 11, 11, 5, 10, 10, 9,
                                          9,  4,  8,  8,  3, 2,  1,  0};
__constant__ unsigned char CHUNK_H[24] = {0, 1, 2, 0, 1, 0, 1, 2, 0, 1, 0, 1,
                                          2, 0, 1, 0, 1, 2, 0, 1, 2, 2, 2, 2};

__global__ __launch_bounds__(256, 4) void flash_attn(
    const u16* __restrict__ q, const u16* __restrict__ k,
    const u16* __restrict__ vP, u16* __restrict__ O,
    float* __restrict__ opart, float* __restrict__ lpart) {
  __shared__ u16 Ks[64][72];     // [s][d]
  __shared__ u16 Vs[64][72];     // [d][u]  (u = permuted s)
  __shared__ u16 Ps[4][32][72];  // per-wave P tile [m][u]

  int tid = threadIdx.x;
  int lane = tid & 63, w = tid >> 6;
  int g = lane >> 4, c = lane & 15;

  int id = blockIdx.x;
  int e = id >> 6, bh = id & 63;
  int x = CHUNK_X[e], hf = CHUNK_H[e];  // hf: 0/1 = key-half, 2 = whole tile
  int sb, se;
  if (hf == 2) {
    sb = 0; se = 2 * x + 2;
  } else {
    int n = x + 1; sb = hf * n; se = sb + n;
  }
  int t0 = x << 7;

  const u16* qb = q + (size_t)bh * TT * DH;
  const u16* kb = k + (size_t)bh * TT * DH;
  const u16* vb = vP + (size_t)bh * DH * TT;

  // Q fragments persistent in registers (A-layout: m=lane&15, k=(lane>>4)*8+j)
  short8 qf[2][2];
#pragma unroll
  for (int mt = 0; mt < 2; ++mt) {
    int qrow = t0 + w * 32 + mt * 16 + c;
#pragma unroll
    for (int kc = 0; kc < 2; ++kc)
      qf[mt][kc] = *(const short8*)(qb + (size_t)qrow * DH + kc * 32 + g * 8);
  }

  const floatx4 zf = {0.f, 0.f, 0.f, 0.f};
  const short8 onesf = {(short)0x3F80, (short)0x3F80, (short)0x3F80,
                        (short)0x3F80, (short)0x3F80, (short)0x3F80,
                        (short)0x3F80, (short)0x3F80};  // bf16 1.0 x8

  floatx4 oacc[2][4];
#pragma unroll
  for (int mt = 0; mt < 2; ++mt)
#pragma unroll
    for (int nt = 0; nt < 4; ++nt) oacc[mt][nt] = zf;
  floatx4 lacc[2];
  lacc[0] = zf;
  lacc[1] = zf;

  // staging: row = tid>>2 (0..63), col base = (tid&3)*16, 2x16B per tensor
  int srow = tid >> 2, scol = (tid & 3) * 16;
  const u16* kbase = kb + (size_t)srow * DH + scol;
  const u16* vbase = vb + (size_t)srow * TT + scol;  // vP rows: [d][t-contig]

  // preload iter sb
  uint4 kr0 = *(const uint4*)(kbase + (size_t)(sb << 6) * DH);
  uint4 kr1 = *(const uint4*)(kbase + (size_t)(sb << 6) * DH + 8);
  uint4 vr0 = *(const uint4*)(vbase + (sb << 6));
  uint4 vr1 = *(const uint4*)(vbase + (sb << 6) + 8);

  int nfull = 2 * x;  // iters >= nfull need the causal mask
  int wmax = t0 + w * 32 + 31;
  for (int it = sb; it < se; ++it) {
    int s0 = it << 6;
    __syncthreads();  // all waves done reading prev tiles
    *(uint4*)(&Ks[srow][scol]) = kr0;
    *(uint4*)(&Ks[srow][scol + 8]) = kr1;
    *(uint4*)(&Vs[srow][scol]) = vr0;
    *(uint4*)(&Vs[srow][scol + 8]) = vr1;
    if (it + 1 < se) {  // prefetch issued BEFORE barrier: regs already
      size_t koff = (size_t)((it + 1) << 6) * DH;  // consumed by ds_writes
      int voff = (it + 1) << 6;
      kr0 = *(const uint4*)(kbase + koff);
      kr1 = *(const uint4*)(kbase + koff + 8);
      vr0 = *(const uint4*)(vbase + voff);
      vr1 = *(const uint4*)(vbase + voff + 8);
    }
    __syncthreads();
    if (s0 > wmax) continue;  // wave-uniform: tile fully masked (last iter)
    bool masked = (it >= nfull);

    // S = Q K^T ; kf shared across both m-tiles; kc=0 uses zero C-operand
    floatx4 z[2][4];
    __builtin_amdgcn_s_setprio(1);
#pragma unroll
    for (int n = 0; n < 4; ++n) {
      short8 kf = *(const short8*)(&Ks[n * 16 + c][g * 8]);
      z[0][n] = MFMA_BF16(qf[0][0], kf, zf, 0, 0, 0);
      z[1][n] = MFMA_BF16(qf[1][0], kf, zf, 0, 0, 0);
    }
#pragma unroll
    for (int n = 0; n < 4; ++n) {
      short8 kf = *(const short8*)(&Ks[n * 16 + c][32 + g * 8]);
      z[0][n] = MFMA_BF16(qf[0][1], kf, z[0][n], 0, 0, 0);
      z[1][n] = MFMA_BF16(qf[1][1], kf, z[1][n], 0, 0, 0);
    }
    __builtin_amdgcn_s_setprio(0);

    // softmax (no offset: uniform scale cancels in the final division);
    // P packed to bf16 by v_perm truncation, b64 stores
#pragma unroll
    for (int mt = 0; mt < 2; ++mt) {
      int qr = t0 + w * 32 + mt * 16 + g * 4;
#pragma unroll
      for (int r = 0; r < 4; ++r) {
        float p0 = exp2f(z[mt][0][r]);
        float p1 = exp2f(z[mt][1][r]);
        float p2 = exp2f(z[mt][2][r]);
        float p3 = exp2f(z[mt][3][r]);
        if (masked) {
          if (s0 + c > qr + r) p0 = 0.f;
          if (s0 + 16 + c > qr + r) p1 = 0.f;
          if (s0 + 32 + c > qr + r) p2 = 0.f;
          if (s0 + 48 + c > qr + r) p3 = 0.f;
        }
        // u-layout: s = n*16+c -> u = 4c+n; 4 values contiguous at u0=4c
        uint2 pk = {pktrunc(p0, p1), pktrunc(p2, p3)};
        *(uint2*)(&Ps[w][mt * 16 + g * 4 + r][4 * c]) = pk;
      }
    }

    // PV + lsum-by-MFMA: vf shared across both m-tiles (intra-wave LDS)
    __builtin_amdgcn_s_setprio(1);
#pragma unroll
    for (int kc = 0; kc < 2; ++kc) {
      short8 pf0 = *(const short8*)(&Ps[w][c][kc * 32 + g * 8]);
      short8 pf1 = *(const short8*)(&Ps[w][16 + c][kc * 32 + g * 8]);
      lacc[0] = MFMA_BF16(pf0, onesf, lacc[0], 0, 0, 0);
      lacc[1] = MFMA_BF16(pf1, onesf, lacc[1], 0, 0, 0);
#pragma unroll
      for (int nt = 0; nt < 4; ++nt) {
        short8 vf = *(const short8*)(&Vs[nt * 16 + c][kc * 32 + g * 8]);
        oacc[0][nt] = MFMA_BF16(pf0, vf, oacc[0][nt], 0, 0, 0);
        oacc[1][nt] = MFMA_BF16(pf1, vf, oacc[1][nt], 0, 0, 0);
      }
    }
    __builtin_amdgcn_s_setprio(0);
  }

  // epilogue: lacc[mt][r] already holds the full row-sum (replicated over c)
  int b = bh >> 4, h = bh & 15;
  if (hf == 2) {
    // light chunk: normalize and write bf16 directly
#pragma unroll
    for (int mt = 0; mt < 2; ++mt) {
      float inv[4];
#pragma unroll
      for (int r = 0; r < 4; ++r) inv[r] = 1.f / lacc[mt][r];
#pragma unroll
      for (int nt = 0; nt < 4; ++nt)
#pragma unroll
        for (int r = 0; r < 4; ++r) {
          int trow = t0 + w * 32 + mt * 16 + g * 4 + r;
          O[((size_t)b * TT + trow) * CC + h * DH + nt * 16 + c] =
              f2bf(oacc[mt][nt][r] * inv[r]);
        }
    }
  } else {
    // heavy half: store raw fp32 partials; merge_heavy combines
    float* os = opart + ((size_t)hf * 65536 + (size_t)bh * 1024) * 64;
    float* ls = lpart + (size_t)hf * 65536 + (size_t)bh * 1024;
#pragma unroll
    for (int mt = 0; mt < 2; ++mt) {
      int r0 = t0 - 1024 + w * 32 + mt * 16 + g * 4;  // local heavy-row base
#pragma unroll
      for (int nt = 0; nt < 4; ++nt)
#pragma unroll
        for (int r = 0; r < 4; ++r)
          os[(size_t)(r0 + r) * 64 + nt * 16 + c] = oacc[mt][nt][r];
      if (c == 0)
#pragma unroll
        for (int r = 0; r < 4; ++r) ls[r0 + r] = lacc[mt][r];
    }
  }
}

// ---------------------------------------------------------------------------
// Merge the two key-half partials for heavy rows (t in [1024, 2048)):
// Ow = (o0 + o1) / (l0 + l1). ~42 MB traffic, memory-bound.
// ---------------------------------------------------------------------------
__global__ __launch_bounds__(256) void merge_heavy(
    const float* __restrict__ op, const float* __restrict__ lp,
    u16* __restrict__ O) {
  int gid = blockIdx.x * 256 + threadIdx.x;  // 64 bh * 1024 rows * 16 chunks
  int dq = gid & 15;                         // float4 chunk within d=64
  int row = gid >> 4;                        // bh*1024 + lr
  float4 a = *(const float4*)(op + (size_t)row * 64 + dq * 4);
  float4 b = *(const float4*)(op + ((size_t)row + 65536) * 64 + dq * 4);
  float inv = 1.f / (lp[row] + lp[row + 65536]);
  int bh = row >> 10, lr = row & 1023;
  int bb = bh >> 4, h = bh & 15;
  u16* dst = O + ((size_t)bb * TT + 1024 + lr) * CC + h * DH + dq * 4;
  uint2 o = {pk2((a.x + b.x) * inv, (a.y + b.y) * inv),
             pk2((a.z + b.z) * inv, (a.w + b.w) * inv)};
  *(uint2*)dst = o;
}

// ---------------------------------------------------------------------------
extern "C" void kernel_launch(void* const* d_in, const int* in_sizes, int n_in,
                              void* d_out, int out_size, void* d_ws,
                              size_t ws_size, hipStream_t stream) {
  const float* x = (const float*)d_in[0];
  const float* Wq = (const float*)d_in[1];
  const float* Wk = (const float*)d_in[2];
  const float* Wv = (const float*)d_in[3];
  const float* Wo = (const float*)d_in[4];
  const float* bo = (const float*)d_in[5];
  float* out = (float*)d_out;

  u16* ws = (u16*)d_ws;
  u16* xb = ws;                        // 8388608  (reused as Ow after QKV GEMM)
  u16* Wt = xb + 8388608;              // 3145728  (dead after gemm_qkv: lpart)
  u16* Wob = Wt + 3145728;             // 1048576
  u16* qw = Wob + 1048576;             // 8388608
  u16* kw = qw + 8388608;              // 8388608
  u16* vw = kw + 8388608;              // 8388608 ([bh][t][d], coalesced)
  u16* vP = vw + 8388608;              // 8388608 (permuted [bh][d][tile][u])
  u16* Ow = xb;                        // alias: xb dead after gemm_qkv
  float* opart = (float*)d_out;        // dead until gemm_bt<1>
  float* lpart = (float*)Wt;           // Wt dead after gemm_qkv

  convert_kernel<<<12288, 256, 0, stream>>>(x, Wq, Wk, Wv, Wo, xb, Wt, Wob);

  gemm_qkv<<<dim3(NQKV / 384, MM / 128), 512, 0, stream>>>(
      xb, Wt, qw, kw, vw);

  vtrans<<<dim3(TT / 64, BB * HH), 256, 0, stream>>>(vw, vP);

  flash_attn<<<dim3(1536), 256, 0, stream>>>(qw, kw, vP, Ow, opart, lpart);

  merge_heavy<<<dim3(4096), 256, 0, stream>>>(opart, lpart, Ow);

  gemm_bt<1><<<dim3(CC / 128, MM / 128), 256, 0, stream>>>(
      Ow, Wob, MM, CC, CC, nullptr, nullptr, nullptr, out, bo);
}